// Round 2
// baseline (265.336 us; speedup 1.0000x reference)
//
#include <hip/hip_runtime.h>

#define HH 512
#define WW 512
#define NPLANE 48
#define TX 64
#define TY 16
#define HALO 5
#define KS 11
#define IR (TY + 2 * HALO)   // 26 intermediate rows
#define LPAD 65              // odd pad: Phase-A strided writes -> conflict-free

// Phase A: horizontal Gaussian blur of 5 channels (p, t, p^2, t^2, p*t),
//          computed in registers from vectorized float4 loads, written to LDS.
// Phase B: vertical blur + SSIM map + block reduction -> atomicAdd into ws.
__global__ __launch_bounds__(256, 4) void ssim_kernel(
    const float* __restrict__ pred, const float* __restrict__ target,
    float* __restrict__ ws_sum)
{
    __shared__ float sh[5][IR][LPAD];   // 5*26*65*4 = 33800 B -> 4 blocks/CU
    __shared__ float red[4];

    // Gaussian weights (normalized), sigma=1.5 -> 2*sigma^2 = 4.5
    float w[KS];
    float s = 0.f;
#pragma unroll
    for (int k = 0; k < KS; ++k) {
        float d = (float)(k - HALO);
        w[k] = __expf(-d * d * (1.0f / 4.5f));
        s += w[k];
    }
    float invs = 1.0f / s;
#pragma unroll
    for (int k = 0; k < KS; ++k) w[k] *= invs;

    const int tid = threadIdx.x;
    const int plane = blockIdx.z;
    const int tx0 = blockIdx.x * TX;
    const int ty0 = blockIdx.y * TY;
    const float* __restrict__ pp = pred + (size_t)plane * HH * WW;
    const float* __restrict__ tp = target + (size_t)plane * HH * WW;

    // ---- Phase A: horizontal blur in registers ----
    // IR rows x 8 col-segments = 208 active threads; each owns 8 output cols.
    if (tid < IR * 8) {
        const int rr = tid >> 3;
        const int seg = tid & 7;
        const int gy = ty0 + rr - HALO;
        const int gbase = tx0 + seg * 8 - 8;   // aligned window start (24 cols)
        float p[24], t[24];
        if (gy >= 0 && gy < HH) {
            const float* __restrict__ prow = pp + (size_t)gy * WW;
            const float* __restrict__ trow = tp + (size_t)gy * WW;
#pragma unroll
            for (int q = 0; q < 6; ++q) {
                int c0 = gbase + q * 4;
                if (c0 >= 0 && c0 <= WW - 4) {
                    float4 vp = *reinterpret_cast<const float4*>(prow + c0);
                    float4 vt = *reinterpret_cast<const float4*>(trow + c0);
                    p[q * 4 + 0] = vp.x; p[q * 4 + 1] = vp.y;
                    p[q * 4 + 2] = vp.z; p[q * 4 + 3] = vp.w;
                    t[q * 4 + 0] = vt.x; t[q * 4 + 1] = vt.y;
                    t[q * 4 + 2] = vt.z; t[q * 4 + 3] = vt.w;
                } else {
#pragma unroll
                    for (int e = 0; e < 4; ++e) {
                        int c = c0 + e;
                        bool v = (c >= 0) && (c < WW);
                        p[q * 4 + e] = v ? prow[c] : 0.f;
                        t[q * 4 + e] = v ? trow[c] : 0.f;
                    }
                }
            }
        } else {
#pragma unroll
            for (int q = 0; q < 24; ++q) { p[q] = 0.f; t[q] = 0.f; }
        }
        // output col j uses inputs [j+3, j+13] within the 24-col window
#pragma unroll
        for (int j = 0; j < 8; ++j) {
            float ap = 0.f, at = 0.f, ap2 = 0.f, at2 = 0.f, apt = 0.f;
#pragma unroll
            for (int k = 0; k < KS; ++k) {
                float pv = p[j + 3 + k], tv = t[j + 3 + k], wk = w[k];
                float wp = wk * pv, wt = wk * tv;
                ap += wp;
                at += wt;
                ap2 = fmaf(wp, pv, ap2);
                at2 = fmaf(wt, tv, at2);
                apt = fmaf(wp, tv, apt);
            }
            int c = seg * 8 + j;
            sh[0][rr][c] = ap;
            sh[1][rr][c] = at;
            sh[2][rr][c] = ap2;
            sh[3][rr][c] = at2;
            sh[4][rr][c] = apt;
        }
    }
    __syncthreads();

    // ---- Phase B: vertical blur + SSIM ----
    // 256 threads = 64 cols x 4 row-groups of 4 rows
    const int col = tid & 63;
    const int r0 = (tid >> 6) * 4;

    float acc[5][4];
#pragma unroll
    for (int ch = 0; ch < 5; ++ch) {
        float win[14];
#pragma unroll
        for (int m = 0; m < 14; ++m) win[m] = sh[ch][r0 + m][col];
#pragma unroll
        for (int j = 0; j < 4; ++j) {
            float a = 0.f;
#pragma unroll
            for (int k = 0; k < KS; ++k) a = fmaf(w[k], win[j + k], a);
            acc[ch][j] = a;
        }
    }

    const float C1 = 1.0e-4f;   // 0.01^2
    const float C2 = 9.0e-4f;   // 0.03^2
    float lsum = 0.f;
#pragma unroll
    for (int j = 0; j < 4; ++j) {
        float mup = acc[0][j], mut = acc[1][j];
        float mupsq = mup * mup, mutsq = mut * mut, mucr = mup * mut;
        float sp2 = acc[2][j] - mupsq;
        float st2 = acc[3][j] - mutsq;
        float scr = acc[4][j] - mucr;
        float n1 = 2.f * mucr + C1;
        float n2 = 2.f * scr + C2;
        float d1 = mupsq + mutsq + C1;
        float d2 = sp2 + st2 + C2;
        lsum += __fdividef(n1 * n2, d1 * d2);
    }

    // wave (64-lane) shuffle reduction
#pragma unroll
    for (int off = 32; off > 0; off >>= 1) lsum += __shfl_down(lsum, off, 64);
    if ((tid & 63) == 0) red[tid >> 6] = lsum;
    __syncthreads();
    if (tid == 0) {
        float tot = red[0] + red[1] + red[2] + red[3];
        atomicAdd(ws_sum, tot);
    }
}

__global__ void finalize_kernel(const float* __restrict__ ws_sum,
                                float* __restrict__ out) {
    out[0] = 1.0f - ws_sum[0] * (1.0f / 12582912.0f);  // N = 16*3*512*512
}

extern "C" void kernel_launch(void* const* d_in, const int* in_sizes, int n_in,
                              void* d_out, int out_size, void* d_ws, size_t ws_size,
                              hipStream_t stream) {
    const float* pred = (const float*)d_in[0];
    const float* target = (const float*)d_in[1];
    float* out = (float*)d_out;
    float* ws = (float*)d_ws;

    hipMemsetAsync(ws, 0, sizeof(float), stream);  // graph-capturable
    dim3 grid(WW / TX, HH / TY, NPLANE);           // 8 x 32 x 48 = 12288 blocks
    ssim_kernel<<<grid, 256, 0, stream>>>(pred, target, ws);
    finalize_kernel<<<1, 1, 0, stream>>>(ws, out);
}

// Round 3
// 177.205 us; speedup vs baseline: 1.4973x; 1.4973x over previous
//
#include <hip/hip_runtime.h>

#define HH 512
#define WW 512
#define NPLANE 48
#define TX 64          // cols per block
#define BY 256         // rows per block
#define CHK 16         // rows per chunk
#define NCHUNK (BY / CHK)
#define HALO 5
#define KS 11
#define RING 32        // ring rows (pow2); live span per chunk = 26+16-? <= 32
#define PITCH 65       // ch-plane pitch; row stride 5*65=325 == 5 (odd) mod 32 -> 2-way banks

// Streaming SSIM: per block, stream 256 rows in 16-row chunks through an LDS
// ring of h-blurred channels (p, t, p^2, t^2, p*t); v-blur + SSIM fused,
// scalar accumulated via one atomicAdd per block.
__global__ __launch_bounds__(256, 3) void ssim_kernel(
    const float* __restrict__ pred, const float* __restrict__ target,
    float* __restrict__ ws_sum)
{
    __shared__ float ring[RING][5][PITCH];   // 32*5*65*4 = 41600 B -> 3 blocks/CU
    __shared__ float red[4];

    // Gaussian weights, sigma=1.5 -> 2*sigma^2 = 4.5
    float w[KS];
    float s = 0.f;
#pragma unroll
    for (int k = 0; k < KS; ++k) {
        float d = (float)(k - HALO);
        w[k] = __expf(-d * d * (1.0f / 4.5f));
        s += w[k];
    }
    float invs = 1.0f / s;
#pragma unroll
    for (int k = 0; k < KS; ++k) w[k] *= invs;

    const int tid = threadIdx.x;
    const int X0 = blockIdx.x * TX;
    const int Y0 = blockIdx.y * BY;
    const int plane = blockIdx.z;
    const float* __restrict__ pp = pred + (size_t)plane * HH * WW;
    const float* __restrict__ tp = target + (size_t)plane * HH * WW;

    // h-role: one row x 4 consecutive cols per thread per chunk
    const int hr = tid >> 4;       // 0..15 row-in-chunk (4 per wave)
    const int hc = tid & 15;       // col-group
    const int cbase = 4 * hc;      // local col base
    // v-role: one col x 4 rows per thread per chunk
    const int vc = tid & 63;
    const int vg = tid >> 6;

    float pr[20], tr[20];          // raw window: global cols [X0+cbase-8, X0+cbase+11]

    auto load_raw = [&](int chunk) {
        const int gy = Y0 + CHK * chunk + HALO + hr;   // rows produced: [16c+5, 16c+20]
        const bool rowok = (gy < HH);                  // gy >= 5 always
        const float* __restrict__ prow = pp + (size_t)gy * WW;
        const float* __restrict__ trow = tp + (size_t)gy * WW;
#pragma unroll
        for (int q = 0; q < 5; ++q) {
            const int c0 = X0 + cbase - 8 + 4 * q;
            float4 vp = make_float4(0.f, 0.f, 0.f, 0.f);
            float4 vt = make_float4(0.f, 0.f, 0.f, 0.f);
            if (rowok) {
                if (c0 >= 0 && c0 <= WW - 4) {
                    vp = *reinterpret_cast<const float4*>(prow + c0);
                    vt = *reinterpret_cast<const float4*>(trow + c0);
                } else {
                    float ep[4], et[4];
#pragma unroll
                    for (int e = 0; e < 4; ++e) {
                        int c = c0 + e;
                        bool ok = (c >= 0) && (c < WW);
                        ep[e] = ok ? prow[c] : 0.f;
                        et[e] = ok ? trow[c] : 0.f;
                    }
                    vp = make_float4(ep[0], ep[1], ep[2], ep[3]);
                    vt = make_float4(et[0], et[1], et[2], et[3]);
                }
            }
            pr[4 * q + 0] = vp.x; pr[4 * q + 1] = vp.y;
            pr[4 * q + 2] = vp.z; pr[4 * q + 3] = vp.w;
            tr[4 * q + 0] = vt.x; tr[4 * q + 1] = vt.y;
            tr[4 * q + 2] = vt.z; tr[4 * q + 3] = vt.w;
        }
    };

    // Prefetch chunk 0's raw rows first (overlaps prologue compute)
    load_raw(0);

    // ---- prologue: h-blur rows rel [-5 .. 4] (slots 27..31,0..4) ----
    for (int t = tid; t < 10 * 64; t += 256) {
        int ry = (t >> 6) - HALO;
        int c = t & 63;
        int gy = Y0 + ry;
        float ap = 0.f, at = 0.f, ap2 = 0.f, at2 = 0.f, apt = 0.f;
        if (gy >= 0 && gy < HH) {
            const float* __restrict__ prow = pp + (size_t)gy * WW;
            const float* __restrict__ trow = tp + (size_t)gy * WW;
#pragma unroll
            for (int k = 0; k < KS; ++k) {
                int gx = X0 + c - HALO + k;
                bool ok = (gx >= 0) && (gx < WW);
                float pv = ok ? prow[gx] : 0.f;
                float tv = ok ? trow[gx] : 0.f;
                float wk = w[k];
                float wp = wk * pv, wt = wk * tv;
                ap += wp; at += wt;
                ap2 = fmaf(wp, pv, ap2);
                at2 = fmaf(wt, tv, at2);
                apt = fmaf(wp, tv, apt);
            }
        }
        int sl = ry & (RING - 1);
        ring[sl][0][c] = ap;
        ring[sl][1][c] = at;
        ring[sl][2][c] = ap2;
        ring[sl][3][c] = at2;
        ring[sl][4][c] = apt;
    }
    // no barrier needed here: chunk-0 h-writes hit slots 5..20, disjoint from
    // prologue slots 27..4; barrier A below orders everything before v-reads.

    const float C1 = 1.0e-4f;
    const float C2 = 9.0e-4f;
    float lsum = 0.f;

    for (int i = 0; i < NCHUNK; ++i) {
        // ---- h-phase: blur row (16i+5+hr), cols cbase..cbase+3, from pr/tr ----
        {
            int sl = (CHK * i + HALO + hr) & (RING - 1);
#pragma unroll
            for (int j = 0; j < 4; ++j) {
                float ap = 0.f, at = 0.f, ap2 = 0.f, at2 = 0.f, apt = 0.f;
#pragma unroll
                for (int k = 0; k < KS; ++k) {
                    float pv = pr[j + 3 + k], tv = tr[j + 3 + k], wk = w[k];
                    float wp = wk * pv, wt = wk * tv;
                    ap += wp; at += wt;
                    ap2 = fmaf(wp, pv, ap2);
                    at2 = fmaf(wt, tv, at2);
                    apt = fmaf(wp, tv, apt);
                }
                int c = cbase + j;
                ring[sl][0][c] = ap;
                ring[sl][1][c] = at;
                ring[sl][2][c] = ap2;
                ring[sl][3][c] = at2;
                ring[sl][4][c] = apt;
            }
        }
        __syncthreads();   // A: ring rows [16i-5, 16i+20] all visible

        if (i + 1 < NCHUNK) load_raw(i + 1);   // prefetch overlaps v-phase

        // ---- v-phase: rows 16i+4vg .. +3, col vc ----
        {
            const int rbase = CHK * i + 4 * vg - HALO;
            const float* rowp[14];
#pragma unroll
            for (int m = 0; m < 14; ++m)
                rowp[m] = &ring[(rbase + m) & (RING - 1)][0][vc];

            float acc[5][4];
#pragma unroll
            for (int ch = 0; ch < 5; ++ch) {
                float win[14];
#pragma unroll
                for (int m = 0; m < 14; ++m) win[m] = rowp[m][ch * PITCH];
#pragma unroll
                for (int j = 0; j < 4; ++j) {
                    float a = 0.f;
#pragma unroll
                    for (int k = 0; k < KS; ++k) a = fmaf(w[k], win[j + k], a);
                    acc[ch][j] = a;
                }
            }
#pragma unroll
            for (int j = 0; j < 4; ++j) {
                float mup = acc[0][j], mut = acc[1][j];
                float mupsq = mup * mup, mutsq = mut * mut, mucr = mup * mut;
                float sp2 = acc[2][j] - mupsq;
                float st2 = acc[3][j] - mutsq;
                float scr = acc[4][j] - mucr;
                float n1 = 2.f * mucr + C1;
                float n2 = 2.f * scr + C2;
                float d1 = mupsq + mutsq + C1;
                float d2 = sp2 + st2 + C2;
                lsum += __fdividef(n1 * n2, d1 * d2);
            }
        }
        __syncthreads();   // B: v-reads done before next chunk's h-writes wrap the ring
    }

    // wave reduction + one atomic per block
#pragma unroll
    for (int off = 32; off > 0; off >>= 1) lsum += __shfl_down(lsum, off, 64);
    if ((tid & 63) == 0) red[tid >> 6] = lsum;
    __syncthreads();
    if (tid == 0) {
        float tot = red[0] + red[1] + red[2] + red[3];
        atomicAdd(ws_sum, tot);
    }
}

__global__ void finalize_kernel(const float* __restrict__ ws_sum,
                                float* __restrict__ out) {
    out[0] = 1.0f - ws_sum[0] * (1.0f / 12582912.0f);  // N = 16*3*512*512
}

extern "C" void kernel_launch(void* const* d_in, const int* in_sizes, int n_in,
                              void* d_out, int out_size, void* d_ws, size_t ws_size,
                              hipStream_t stream) {
    const float* pred = (const float*)d_in[0];
    const float* target = (const float*)d_in[1];
    float* out = (float*)d_out;
    float* ws = (float*)d_ws;

    hipMemsetAsync(ws, 0, sizeof(float), stream);  // graph-capturable
    dim3 grid(WW / TX, HH / BY, NPLANE);           // 8 x 2 x 48 = 768 blocks = 3.0/CU
    ssim_kernel<<<grid, 256, 0, stream>>>(pred, target, ws);
    finalize_kernel<<<1, 1, 0, stream>>>(ws, out);
}

// Round 4
// 154.409 us; speedup vs baseline: 1.7184x; 1.1476x over previous
//
#include <hip/hip_runtime.h>

#define HH 512
#define WW 512
#define NPLANE 48
#define BY 128
#define CHK 16
#define NCH (BY / CHK)   // 8 chunks per block
#define SLOTS 40         // ring slots per col; 40 = 5*8 keeps quad b128 reads 8-aligned
#define KS 11

typedef __attribute__((ext_vector_type(8))) short short8;   // 8 bf16 (A/B frag)
typedef __attribute__((ext_vector_type(4))) float floatx4;  // 4 fp32 (C/D frag)

__device__ inline unsigned pk2bf(float a, float b) {
    union { float f; unsigned u; } ua, ub;
    ua.f = a; ub.f = b;
    unsigned lo = (ua.u + 0x7FFFu + ((ua.u >> 16) & 1u)) >> 16;  // RNE
    unsigned hi = (ub.u + 0x7FFFu + ((ub.u >> 16) & 1u)) >> 16;
    return lo | (hi << 16);
}

// Fully-MFMA SSIM: h-blur = data x W (banded), v-blur = W x ring.
// Each wave owns a private 16-col tile + private LDS ring strip -> no barriers
// in the streaming loop. Intermediates (p,t,p2,t2,pt h-blurred) in bf16.
__global__ __launch_bounds__(256, 4) void ssim_kernel(
    const float* __restrict__ pred, const float* __restrict__ target,
    float* __restrict__ ws_sum)
{
    // ring[wave][ch][col][slot], bf16: 4*5*16*40*2 = 25600 B
    __shared__ __align__(16) short ring[4][5][16][SLOTS];
    __shared__ float red[4];

    const int tid = threadIdx.x;
    const int wv = tid >> 6;
    const int lane = tid & 63;
    const int m = lane & 15;     // A-row / B-col / C-col index
    const int quad = lane >> 4;  // k-group / C-row-group

    // Gaussian weights, sigma=1.5
    float wsum = 0.f;
#pragma unroll
    for (int k = 0; k < KS; ++k) {
        float d = (float)(k - 5);
        wsum += __expf(-d * d * (1.0f / 4.5f));
    }
    const float invs = 1.0f / wsum;

    // Banded weight fragment: value at k=quad*8+j is w[k - m - 3] (0 outside band).
    // Serves as B in h-mfma (B[k][n]=w[k-n-3]) and A in v-mfma (A[m][k]=w[k-m-3]).
    short8 Wf;
    {
        union { short8 v; unsigned u[4]; } W;
#pragma unroll
        for (int jj = 0; jj < 4; ++jj) {
            float v0, v1;
            {
                int idx = quad * 8 + 2 * jj - m - 3;
                float d = (float)(idx - 5);
                v0 = (idx >= 0 && idx < KS) ? __expf(-d * d * (1.0f / 4.5f)) * invs : 0.f;
            }
            {
                int idx = quad * 8 + 2 * jj + 1 - m - 3;
                float d = (float)(idx - 5);
                v1 = (idx >= 0 && idx < KS) ? __expf(-d * d * (1.0f / 4.5f)) * invs : 0.f;
            }
            W.u[jj] = pk2bf(v0, v1);
        }
        Wf = W.v;
    }

    const size_t poff = (size_t)blockIdx.z * HH * WW;
    const float* __restrict__ pp = pred + poff;
    const float* __restrict__ tp = target + poff;
    const int X0 = blockIdx.x * 64 + wv * 16;  // wave's 16-col tile
    const int rawX = X0 - 8;                   // 32-col raw window base
    const int Y0 = blockIdx.y * BY;

    const float C1 = 1.0e-4f;
    const float C2 = 9.0e-4f;
    float lsum = 0.f;
    const floatx4 z = {0.f, 0.f, 0.f, 0.f};

    // h-step k: produce h-blurred rows [Y0+16k-8, Y0+16k+7] into ring at slot base sb
    auto h_step = [&](int k, int sb) {
        const int row = Y0 + CHK * k - 8 + m;
        const bool rowok = ((unsigned)row < (unsigned)HH);
        const int c0 = rawX + quad * 8;
        float4 p0 = {0, 0, 0, 0}, p1 = {0, 0, 0, 0};
        float4 t0 = {0, 0, 0, 0}, t1 = {0, 0, 0, 0};
        if (rowok) {
            const float* pr = pp + (size_t)row * WW;
            const float* tr = tp + (size_t)row * WW;
            if ((unsigned)c0 < (unsigned)WW) {
                p0 = *(const float4*)(pr + c0);
                t0 = *(const float4*)(tr + c0);
            }
            if ((unsigned)(c0 + 4) < (unsigned)WW) {
                p1 = *(const float4*)(pr + c0 + 4);
                t1 = *(const float4*)(tr + c0 + 4);
            }
        }
        const float p[8] = {p0.x, p0.y, p0.z, p0.w, p1.x, p1.y, p1.z, p1.w};
        const float t[8] = {t0.x, t0.y, t0.z, t0.w, t1.x, t1.y, t1.z, t1.w};
        union { short8 v; unsigned u[4]; } Fp, Ft, Fpp, Ftt, Fpt;
#pragma unroll
        for (int jj = 0; jj < 4; ++jj) {
            const float a0 = p[2 * jj], a1 = p[2 * jj + 1];
            const float b0 = t[2 * jj], b1 = t[2 * jj + 1];
            Fp.u[jj]  = pk2bf(a0, a1);
            Ft.u[jj]  = pk2bf(b0, b1);
            Fpp.u[jj] = pk2bf(a0 * a0, a1 * a1);
            Ftt.u[jj] = pk2bf(b0 * b0, b1 * b1);
            Fpt.u[jj] = pk2bf(a0 * b0, a1 * b1);
        }
        floatx4 Dp  = __builtin_amdgcn_mfma_f32_16x16x32_bf16(Fp.v,  Wf, z, 0, 0, 0);
        floatx4 Dt  = __builtin_amdgcn_mfma_f32_16x16x32_bf16(Ft.v,  Wf, z, 0, 0, 0);
        floatx4 Dpp = __builtin_amdgcn_mfma_f32_16x16x32_bf16(Fpp.v, Wf, z, 0, 0, 0);
        floatx4 Dtt = __builtin_amdgcn_mfma_f32_16x16x32_bf16(Ftt.v, Wf, z, 0, 0, 0);
        floatx4 Dpt = __builtin_amdgcn_mfma_f32_16x16x32_bf16(Fpt.v, Wf, z, 0, 0, 0);
        // C-layout: col = lane&15 (=m), rows = quad*4 + reg -> slots sb+quad*4+reg
        int slot = sb + quad * 4;
        if (slot >= SLOTS) slot -= SLOTS;
        {
            uint2 v;
            v.x = pk2bf(Dp[0], Dp[1]);  v.y = pk2bf(Dp[2], Dp[3]);
            *(uint2*)&ring[wv][0][m][slot] = v;
            v.x = pk2bf(Dt[0], Dt[1]);  v.y = pk2bf(Dt[2], Dt[3]);
            *(uint2*)&ring[wv][1][m][slot] = v;
            v.x = pk2bf(Dpp[0], Dpp[1]); v.y = pk2bf(Dpp[2], Dpp[3]);
            *(uint2*)&ring[wv][2][m][slot] = v;
            v.x = pk2bf(Dtt[0], Dtt[1]); v.y = pk2bf(Dtt[2], Dtt[3]);
            *(uint2*)&ring[wv][3][m][slot] = v;
            v.x = pk2bf(Dpt[0], Dpt[1]); v.y = pk2bf(Dpt[2], Dpt[3]);
            *(uint2*)&ring[wv][4][m][slot] = v;
        }
    };

    // v-step: consume 32-slot window starting at vb -> 16 output rows, SSIM
    auto v_step = [&](int vb) {
        int sq = vb + quad * 8;
        if (sq >= SLOTS) sq -= SLOTS;
        const short8 Bp  = *(const short8*)&ring[wv][0][m][sq];
        const short8 Bt  = *(const short8*)&ring[wv][1][m][sq];
        const short8 Bpp = *(const short8*)&ring[wv][2][m][sq];
        const short8 Btt = *(const short8*)&ring[wv][3][m][sq];
        const short8 Bpt = *(const short8*)&ring[wv][4][m][sq];
        floatx4 Mp  = __builtin_amdgcn_mfma_f32_16x16x32_bf16(Wf, Bp,  z, 0, 0, 0);
        floatx4 Mt  = __builtin_amdgcn_mfma_f32_16x16x32_bf16(Wf, Bt,  z, 0, 0, 0);
        floatx4 Mpp = __builtin_amdgcn_mfma_f32_16x16x32_bf16(Wf, Bpp, z, 0, 0, 0);
        floatx4 Mtt = __builtin_amdgcn_mfma_f32_16x16x32_bf16(Wf, Btt, z, 0, 0, 0);
        floatx4 Mpt = __builtin_amdgcn_mfma_f32_16x16x32_bf16(Wf, Bpt, z, 0, 0, 0);
#pragma unroll
        for (int r = 0; r < 4; ++r) {
            const float mup = Mp[r], mut = Mt[r];
            const float mupsq = mup * mup, mutsq = mut * mut, mucr = mup * mut;
            const float sp2 = Mpp[r] - mupsq;
            const float st2 = Mtt[r] - mutsq;
            const float scr = Mpt[r] - mucr;
            const float n1 = 2.f * mucr + C1;
            const float n2 = 2.f * scr + C2;
            const float d1 = mupsq + mutsq + C1;
            const float d2 = sp2 + st2 + C2;
            lsum += __fdividef(n1 * n2, d1 * d2);
        }
    };

    // Software pipeline: h(0), then { h(i+1); v(i) } -- wave-private, no barriers.
    int hb = SLOTS - 8;  // (-8) mod 40
    int vb = SLOTS - 8;
    h_step(0, hb);
    hb += CHK; if (hb >= SLOTS) hb -= SLOTS;
    for (int i = 0; i < NCH; ++i) {
        h_step(i + 1, hb);
        hb += CHK; if (hb >= SLOTS) hb -= SLOTS;
        v_step(vb);
        vb += CHK; if (vb >= SLOTS) vb -= SLOTS;
    }

    // wave reduce -> block reduce -> one atomic per block
#pragma unroll
    for (int off = 32; off > 0; off >>= 1) lsum += __shfl_down(lsum, off, 64);
    if (lane == 0) red[wv] = lsum;
    __syncthreads();
    if (tid == 0) {
        atomicAdd(ws_sum, red[0] + red[1] + red[2] + red[3]);
    }
}

__global__ void finalize_kernel(const float* __restrict__ ws_sum,
                                float* __restrict__ out) {
    out[0] = 1.0f - ws_sum[0] * (1.0f / 12582912.0f);  // N = 16*3*512*512
}

extern "C" void kernel_launch(void* const* d_in, const int* in_sizes, int n_in,
                              void* d_out, int out_size, void* d_ws, size_t ws_size,
                              hipStream_t stream) {
    const float* pred = (const float*)d_in[0];
    const float* target = (const float*)d_in[1];
    float* out = (float*)d_out;
    float* ws = (float*)d_ws;

    hipMemsetAsync(ws, 0, sizeof(float), stream);       // graph-capturable
    dim3 grid(WW / 64, HH / BY, NPLANE);                // 8 x 4 x 48 = 1536 blocks
    ssim_kernel<<<grid, 256, 0, stream>>>(pred, target, ws);
    finalize_kernel<<<1, 1, 0, stream>>>(ws, out);
}